// Round 1
// baseline (218.592 us; speedup 1.0000x reference)
//
#include <hip/hip_runtime.h>
#include <math.h>

// Problem: ContrastiveLoss — x (8,128,16,8,8) fp32.
// feats[n,f] = x_flat[b*131072 + f*1024 + r], n=(b<<10)|r, N=8192, F=128.
// loss = logsumexp_{i!=j}( (x̂_i · x̂_j) / 0.1 )
// Unit rows => s<=10 exactly, so lse = 10 + ln(sum exp(s-10)) with no max pass.
//
// ws layout:
//   partials: double[16384]        @ 0        (128 KB)  one per tile-block
//   Xt:       float[128*8192]      @ 131072   (4 MB)    normalized, [F,N] layout
// Total ws use: 4,325,376 B.

#define N_ROWS 8192
#define F_DIM  128
#define R_DIM  1024

// ---------------------------------------------------------------------------
// Kernel 1: row norms + write normalized X^T in [F, N] layout (coalesced).
// grid 32 x 256 threads, one thread per row n.
// ---------------------------------------------------------------------------
__global__ __launch_bounds__(256)
void normalize_kernel(const float* __restrict__ x, float* __restrict__ Xt) {
    int n = blockIdx.x * 256 + threadIdx.x;
    int b = n >> 10;
    int r = n & 1023;
    const float* px = x + b * (F_DIM * R_DIM) + r;
    float ss = 0.f;
#pragma unroll 8
    for (int f = 0; f < F_DIM; ++f) {
        float v = px[f * R_DIM];
        ss = fmaf(v, v, ss);
    }
    float nrm = fmaxf(sqrtf(ss), 1e-12f);
    float inv = 1.0f / nrm;
    // second pass re-reads from L2 (4 MB input, cache-resident)
#pragma unroll 8
    for (int f = 0; f < F_DIM; ++f) {
        Xt[f * N_ROWS + n] = px[f * R_DIM] * inv;
    }
}

// ---------------------------------------------------------------------------
// Kernel 2: 64x64 Gram tile + fused exp-accumulate.
// Grid (128,128); blocks with J<I write 0 and exit (symmetry: off-diag tiles
// counted once with weight 2; diagonal tiles weight 1, skip i==j).
// LDS: 2 x [128][64] fp32 = 64 KB exactly -> 2 blocks/CU.
// ---------------------------------------------------------------------------
__global__ __launch_bounds__(256)
void gram_lse_kernel(const float* __restrict__ Xt, double* __restrict__ partials) {
    const int I = blockIdx.x, J = blockIdx.y;
    const int bid = blockIdx.y * gridDim.x + blockIdx.x;
    if (J < I) {
        if (threadIdx.x == 0) partials[bid] = 0.0;  // ws is poisoned; must zero
        return;
    }
    __shared__ float lA[F_DIM][64];
    __shared__ float lB[F_DIM][64];
    const int tid = threadIdx.x;
    const float* gA = Xt + I * 64;
    const float* gB = Xt + J * 64;
    // 8192 floats per tile; 256 threads x 8 float4 each, coalesced rows of 64.
#pragma unroll
    for (int p = 0; p < 8; ++p) {
        int e = p * 1024 + tid * 4;
        int f = e >> 6;
        int i = e & 63;
        *(float4*)(&lA[f][i]) = *(const float4*)(gA + f * N_ROWS + i);
        *(float4*)(&lB[f][i]) = *(const float4*)(gB + f * N_ROWS + i);
    }
    __syncthreads();

    const int i0 = (tid & 15) * 4;
    const int j0 = (tid >> 4) * 4;
    float acc[4][4] = {{0.f}};
#pragma unroll 8
    for (int f = 0; f < F_DIM; ++f) {
        float4 a = *(const float4*)(&lA[f][i0]);
        float4 b = *(const float4*)(&lB[f][j0]);
        acc[0][0] = fmaf(a.x, b.x, acc[0][0]);
        acc[0][1] = fmaf(a.x, b.y, acc[0][1]);
        acc[0][2] = fmaf(a.x, b.z, acc[0][2]);
        acc[0][3] = fmaf(a.x, b.w, acc[0][3]);
        acc[1][0] = fmaf(a.y, b.x, acc[1][0]);
        acc[1][1] = fmaf(a.y, b.y, acc[1][1]);
        acc[1][2] = fmaf(a.y, b.z, acc[1][2]);
        acc[1][3] = fmaf(a.y, b.w, acc[1][3]);
        acc[2][0] = fmaf(a.z, b.x, acc[2][0]);
        acc[2][1] = fmaf(a.z, b.y, acc[2][1]);
        acc[2][2] = fmaf(a.z, b.z, acc[2][2]);
        acc[2][3] = fmaf(a.z, b.w, acc[2][3]);
        acc[3][0] = fmaf(a.w, b.x, acc[3][0]);
        acc[3][1] = fmaf(a.w, b.y, acc[3][1]);
        acc[3][2] = fmaf(a.w, b.z, acc[3][2]);
        acc[3][3] = fmaf(a.w, b.w, acc[3][3]);
    }

    const bool diagTile = (I == J);
    float lsum = 0.f;
#pragma unroll
    for (int ii = 0; ii < 4; ++ii) {
#pragma unroll
        for (int jj = 0; jj < 4; ++jj) {
            if (diagTile && (i0 + ii == j0 + jj)) continue;
            // s = 10 * dot ; exp(s - 10), arg in [-20, 0] — no overflow
            lsum += __expf(fmaf(10.0f, acc[ii][jj], -10.0f));
        }
    }
    double dsum = diagTile ? (double)lsum : 2.0 * (double)lsum;

    // wave reduce (64 lanes) then cross-wave via LDS (reuse lA after barrier)
#pragma unroll
    for (int off = 32; off > 0; off >>= 1)
        dsum += __shfl_down(dsum, off, 64);
    __syncthreads();  // all lA/lB reads complete before aliasing
    double* red = (double*)&lA[0][0];
    const int lane = tid & 63, wid = tid >> 6;
    if (lane == 0) red[wid] = dsum;
    __syncthreads();
    if (tid == 0) partials[bid] = red[0] + red[1] + red[2] + red[3];
}

// ---------------------------------------------------------------------------
// Kernel 3: reduce 16384 partials, out = 10 + ln(sum)   (NEGATIVE_WEIGHT = 1)
// ---------------------------------------------------------------------------
__global__ __launch_bounds__(256)
void final_kernel(const double* __restrict__ partials, float* __restrict__ out) {
    double s = 0.0;
    for (int i = threadIdx.x; i < 16384; i += 256) s += partials[i];
    __shared__ double red[256];
    red[threadIdx.x] = s;
    __syncthreads();
    for (int stride = 128; stride > 0; stride >>= 1) {
        if (threadIdx.x < stride) red[threadIdx.x] += red[threadIdx.x + stride];
        __syncthreads();
    }
    if (threadIdx.x == 0) out[0] = (float)(10.0 + log(red[0]));
}

extern "C" void kernel_launch(void* const* d_in, const int* in_sizes, int n_in,
                              void* d_out, int out_size, void* d_ws, size_t ws_size,
                              hipStream_t stream) {
    const float* x = (const float*)d_in[0];
    float* out = (float*)d_out;
    double* partials = (double*)d_ws;                      // 16384 doubles
    float* Xt = (float*)((char*)d_ws + 131072);            // 4 MB, [F,N]

    normalize_kernel<<<32, 256, 0, stream>>>(x, Xt);
    dim3 grid(128, 128);
    gram_lse_kernel<<<grid, 256, 0, stream>>>(Xt, partials);
    final_kernel<<<1, 256, 0, stream>>>(partials, out);
}

// Round 2
// 91.245 us; speedup vs baseline: 2.3957x; 2.3957x over previous
//
#include <hip/hip_runtime.h>
#include <math.h>

// ContrastiveLoss — x (8,128,16,8,8) fp32.
// feats[n,f] = x[b*131072 + f*1024 + r], n=(b<<10)|r, N=8192, F=128.
// loss = 10 + ln( sum_{i!=j} exp(10*dot(x̂_i,x̂_j) - 10) )   (unit rows => s<=10)
//
// Round 2: bf16 MFMA Gram. X̂ stored pre-swizzled so tile staging is a linear
// 32KB copy and every LDS fragment read is a lane-linear ds_read_b128.
//
// Swizzled layout: row-group rg = n>>4 (16 rows, 4KB each). Within a group,
// 16B chunk index = t*64 + quad*16 + (n&15), where k = t*32 + quad*8 + j.
// This equals the order lane l (=quad*16+r) of the MFMA frag read wants.
//
// ws: partials double[4096] @0 (32KB); Xs bf16[8192*128] @32768 (2MB).

#define N_ROWS 8192
#define F_DIM  128
#define R_DIM  1024

typedef __attribute__((ext_vector_type(8))) short short8;
typedef __bf16 bf16_t;
typedef __attribute__((ext_vector_type(8))) bf16_t bf16x8;
typedef __attribute__((ext_vector_type(4))) float f32x4;

// Adapter: compiles whether the mfma builtin takes short8 or bf16x8 operands.
struct Frag {
    short8 s;
    __device__ operator short8() const { return s; }
    __device__ operator bf16x8() const { return __builtin_bit_cast(bf16x8, s); }
};

__device__ inline short f2bf(float f) {  // RNE fp32->bf16 (inputs finite)
    unsigned u = __float_as_uint(f);
    u += 0x7fff + ((u >> 16) & 1);
    return (short)(u >> 16);
}

// ---------------------------------------------------------------------------
// Kernel 1: row norms (fp32) + write swizzled bf16 X̂. One thread per row.
// ---------------------------------------------------------------------------
__global__ __launch_bounds__(256)
void normalize_kernel(const float* __restrict__ x, short* __restrict__ Xs) {
    int n = blockIdx.x * 256 + threadIdx.x;
    int b = n >> 10, r = n & 1023;
    const float* px = x + b * (F_DIM * R_DIM) + r;   // stride R_DIM over f, lane-coalesced
    float ss = 0.f;
#pragma unroll 8
    for (int f = 0; f < F_DIM; ++f) { float v = px[f * R_DIM]; ss = fmaf(v, v, ss); }
    float inv = 1.0f / fmaxf(sqrtf(ss), 1e-12f);
    short* base = Xs + (n >> 4) * 2048;              // row-group base (shorts)
    const int rr = n & 15;
#pragma unroll
    for (int t = 0; t < 4; ++t)
#pragma unroll
        for (int q = 0; q < 4; ++q) {
            union { short s[8]; int4 v; } u;
#pragma unroll
            for (int j = 0; j < 8; ++j) {
                int k = t * 32 + q * 8 + j;
                u.s[j] = f2bf(px[k * R_DIM] * inv);
            }
            *(int4*)(base + (t * 64 + q * 16 + rr) * 8) = u.v;
        }
}

// ---------------------------------------------------------------------------
// Kernel 2: 128x128 Gram tile via mfma_f32_16x16x32_bf16 + fused exp-sum.
// Grid (64,64); J<I blocks zero their partial and exit (symmetry weight 2).
// LDS 64KB (A 32KB + B 32KB) -> 2 blocks/CU. 4 waves, each a 64x64 region.
// ---------------------------------------------------------------------------
__global__ __launch_bounds__(256)
void gram_lse_kernel(const short* __restrict__ Xs, double* __restrict__ partials) {
    const int I = blockIdx.x, J = blockIdx.y;
    const int bid = blockIdx.y * gridDim.x + blockIdx.x;
    const int tid = threadIdx.x;
    if (J < I) { if (tid == 0) partials[bid] = 0.0; return; }

    __shared__ short lds[32768];  // A chunks [0,2048), B chunks [2048,4096)
    {
        const int4* srcA = (const int4*)(Xs + I * 16384);  // 8 row-groups, contiguous
        const int4* srcB = (const int4*)(Xs + J * 16384);
        int4* dst = (int4*)lds;
#pragma unroll
        for (int q = 0; q < 8; ++q) {
            dst[q * 256 + tid]        = srcA[q * 256 + tid];
            dst[2048 + q * 256 + tid] = srcB[q * 256 + tid];
        }
    }
    __syncthreads();

    const int lane = tid & 63;
    const int w    = tid >> 6;
    const int gi0  = (w & 1) * 4;   // 16-row tile base within block rows
    const int gj0  = (w >> 1) * 4;  // within block cols

    f32x4 acc[4][4];
#pragma unroll
    for (int i = 0; i < 4; ++i)
#pragma unroll
        for (int j = 0; j < 4; ++j) acc[i][j] = (f32x4){0.f, 0.f, 0.f, 0.f};

    const short8* ldsA = (const short8*)lds;             // chunk-indexed (16B)
    const short8* ldsB = (const short8*)(lds + 16384);
#pragma unroll
    for (int t = 0; t < 4; ++t) {                        // K-steps of 32
        short8 a[4], b[4];
#pragma unroll
        for (int i = 0; i < 4; ++i) a[i] = ldsA[(gi0 + i) * 256 + t * 64 + lane];
#pragma unroll
        for (int j = 0; j < 4; ++j) b[j] = ldsB[(gj0 + j) * 256 + t * 64 + lane];
#pragma unroll
        for (int i = 0; i < 4; ++i)
#pragma unroll
            for (int j = 0; j < 4; ++j)
                acc[i][j] = __builtin_amdgcn_mfma_f32_16x16x32_bf16(
                    Frag{a[i]}, Frag{b[j]}, acc[i][j], 0, 0, 0);
    }

    // Epilogue: C/D layout col=lane&15, row=(lane>>4)*4+reg  (verified m89/m91)
    const bool diagT = (I == J);
    const int quad = lane >> 4, colL = lane & 15;
    float lsum = 0.f;
#pragma unroll
    for (int i = 0; i < 4; ++i) {
        const int rbase = I * 128 + (gi0 + i) * 16 + quad * 4;
#pragma unroll
        for (int j = 0; j < 4; ++j) {
            const int cbase = J * 128 + (gj0 + j) * 16 + colL;
#pragma unroll
            for (int g = 0; g < 4; ++g) {
                if (diagT && (rbase + g == cbase)) continue;
                lsum += __expf(fmaf(10.0f, acc[i][j][g], -10.0f));
            }
        }
    }
    double dsum = diagT ? (double)lsum : 2.0 * (double)lsum;
#pragma unroll
    for (int off = 32; off > 0; off >>= 1) dsum += __shfl_down(dsum, off, 64);
    __shared__ double red[4];
    if (lane == 0) red[w] = dsum;
    __syncthreads();
    if (tid == 0) partials[bid] = red[0] + red[1] + red[2] + red[3];
}

// ---------------------------------------------------------------------------
// Kernel 3: out = 10 + ln(sum of partials)
// ---------------------------------------------------------------------------
__global__ __launch_bounds__(256)
void final_kernel(const double* __restrict__ partials, float* __restrict__ out) {
    double s = 0.0;
    for (int i = threadIdx.x; i < 4096; i += 256) s += partials[i];
    __shared__ double red[256];
    red[threadIdx.x] = s;
    __syncthreads();
    for (int st = 128; st > 0; st >>= 1) {
        if (threadIdx.x < st) red[threadIdx.x] += red[threadIdx.x + st];
        __syncthreads();
    }
    if (threadIdx.x == 0) out[0] = (float)(10.0 + log(red[0]));
}

extern "C" void kernel_launch(void* const* d_in, const int* in_sizes, int n_in,
                              void* d_out, int out_size, void* d_ws, size_t ws_size,
                              hipStream_t stream) {
    const float* x = (const float*)d_in[0];
    float* out = (float*)d_out;
    double* partials = (double*)d_ws;             // 4096 doubles
    short* Xs = (short*)((char*)d_ws + 32768);    // 2MB swizzled bf16 X̂

    normalize_kernel<<<32, 256, 0, stream>>>(x, Xs);
    gram_lse_kernel<<<dim3(64, 64), 256, 0, stream>>>(Xs, partials);
    final_kernel<<<1, 256, 0, stream>>>(partials, out);
}